// Round 5
// baseline (218.386 us; speedup 1.0000x reference)
//
#include <hip/hip_runtime.h>
#include <hip/hip_cooperative_groups.h>
#include <hip/hip_bf16.h>
#include <cmath>

namespace cg = cooperative_groups;

// GraphAttention: out = elu((softmax(mask_diag(lrelu(si+sj'))) + I) @ h), h = x@W^T + b
// B=8 N=2048 IN=256 H=128, ALPHA=0.2. adj_identity is broadcast eye(N).
//
// Sorted-prefix algorithm: w_ij = (sj_j > -si_i) ? e1_i*f1_j : e2_i*f2_j.
// Sort j by sj desc -> branch-1 set is a prefix; k_i = #{j: sj_j > -si_i}.
// k_i is monotone in si_i, so rows sorted by si have ascending k -> the block
// owning scan positions [r0,r0+32) also finishes rows with k in that range
// (fused epilogue; S1/S2R never hit global memory).
//
// R5: K1 (GEMM) + ONE cooperative kernel (rank/stats -> chunk sums ->
// shfl-scan offsets -> in-LDS scan + fused epilogue), 3 grid.sync()s.

#define ALPHA 0.2f
#define NN 2048
#define NIN 256
#define NH 128
#define NBLK 512

typedef __attribute__((ext_vector_type(8))) short short8;
typedef __attribute__((ext_vector_type(4))) float f32x4;
typedef __attribute__((ext_vector_type(4))) int i32x4;

__device__ __forceinline__ unsigned short f2bf(float f) {
    unsigned int u = __float_as_uint(f);
    u += 0x7fffu + ((u >> 16) & 1u);
    return (unsigned short)(u >> 16);
}

// ---------------------------------------------------------------------------
// K1: h = x @ W^T + b (bf16 MFMA, fp32 accum) + si/sj. Grid 256 x 256thr.
// ---------------------------------------------------------------------------
__global__ __launch_bounds__(256) void k1_h(
    const float* __restrict__ x, const float* __restrict__ Wm,
    const float* __restrict__ bias, const float* __restrict__ av,
    float* __restrict__ hout, float* __restrict__ si, float* __restrict__ sj)
{
    __shared__ __align__(16) unsigned short xls[64 * 264];
    __shared__ __align__(16) unsigned short Wls[128 * 264];
    __shared__ float a1l[128], a2l[128], bl[128];

    const int t = threadIdx.x;
    const int r0 = blockIdx.x * 64;

    for (int p = 0; p < 16; ++p) {
        int idx = p * 256 + t;
        int row = idx >> 6, kq = idx & 63;
        f32x4 v = *(const f32x4*)(x + (size_t)(r0 + row) * NIN + kq * 4);
        unsigned int lo = (unsigned)f2bf(v[0]) | ((unsigned)f2bf(v[1]) << 16);
        unsigned int hi = (unsigned)f2bf(v[2]) | ((unsigned)f2bf(v[3]) << 16);
        *(uint2*)(&xls[row * 264 + kq * 4]) = make_uint2(lo, hi);
    }
    for (int p = 0; p < 32; ++p) {
        int idx = p * 256 + t;
        int row = idx >> 6, kq = idx & 63;
        f32x4 v = *(const f32x4*)(Wm + (size_t)row * NIN + kq * 4);
        unsigned int lo = (unsigned)f2bf(v[0]) | ((unsigned)f2bf(v[1]) << 16);
        unsigned int hi = (unsigned)f2bf(v[2]) | ((unsigned)f2bf(v[3]) << 16);
        *(uint2*)(&Wls[row * 264 + kq * 4]) = make_uint2(lo, hi);
    }
    if (t < 128) { a1l[t] = av[t]; a2l[t] = av[128 + t]; bl[t] = bias[t]; }
    __syncthreads();

    const int w = t >> 6, l = t & 63, la = l & 15, g = l >> 4;

    f32x4 acc[8];
#pragma unroll
    for (int n = 0; n < 8; ++n) acc[n] = (f32x4){0.f, 0.f, 0.f, 0.f};

#pragma unroll
    for (int ks = 0; ks < 8; ++ks) {
        short8 af = *(const short8*)(&xls[(w * 16 + la) * 264 + ks * 32 + g * 8]);
#pragma unroll
        for (int n = 0; n < 8; ++n) {
            short8 bfr = *(const short8*)(&Wls[(n * 16 + la) * 264 + ks * 32 + g * 8]);
            acc[n] = __builtin_amdgcn_mfma_f32_16x16x32_bf16(af, bfr, acc[n], 0, 0, 0);
        }
    }

    float s1[4] = {0.f, 0.f, 0.f, 0.f}, s2[4] = {0.f, 0.f, 0.f, 0.f};
#pragma unroll
    for (int n = 0; n < 8; ++n) {
        int col = n * 16 + la;
#pragma unroll
        for (int r = 0; r < 4; ++r) {
            float v = acc[n][r] + bl[col];
            int row = w * 16 + g * 4 + r;
            hout[(size_t)(r0 + row) * NH + col] = v;
            s1[r] += v * a1l[col];
            s2[r] += v * a2l[col];
        }
    }
#pragma unroll
    for (int r = 0; r < 4; ++r) {
#pragma unroll
        for (int m = 1; m < 16; m <<= 1) {
            s1[r] += __shfl_xor(s1[r], m, 64);
            s2[r] += __shfl_xor(s2[r], m, 64);
        }
    }
    if (la == 0) {
#pragma unroll
        for (int r = 0; r < 4; ++r) {
            int row = w * 16 + g * 4 + r;
            si[r0 + row] = s1[r];
            sj[r0 + row] = s2[r];
        }
    }
}

// ---------------------------------------------------------------------------
// Cooperative kernel: 512 blocks x 256 thr (LDS ~51KB -> 3 blocks/CU >= co-res)
// ---------------------------------------------------------------------------
union ShMem {
    struct {
        float sjl[NN]; float sil[NN];
        int red[32][8][3];
        float mr1[4], mr2[4];
    } a;
    struct { int pl[32]; float f1l[32], f2l[32]; } b;
    struct {
        float hls[32][128];
        float S1[33][128]; float S2[33][128];
        float f1l[32], f2l[32]; int pl[32];
        float ff1[33], ff2[33];
        int redc[4][2]; int lohi[2];
    } c;
};

__global__ __launch_bounds__(256) void kcoop(
    const float* __restrict__ h, const float* __restrict__ si, const float* __restrict__ sj,
    float* __restrict__ e1, float* __restrict__ e2, float* __restrict__ own,
    float* __restrict__ f1s, float* __restrict__ f2s,
    int* __restrict__ karr, int* __restrict__ rowid, int* __restrict__ perm,
    float* __restrict__ cS1, float* __restrict__ cS2,
    float* __restrict__ cF1, float* __restrict__ cF2,
    float* __restrict__ out)
{
    __shared__ __align__(16) ShMem U;
    cg::grid_group grid = cg::this_grid();
    const int t = threadIdx.x;
    const int blk = blockIdx.x;
    const int wave = t >> 6, lane = t & 63;

    // ===================== Phase A: ranks + stats =====================
    {
        const int b = blk >> 6, j0 = (blk & 63) * 32;
        const int gbase = b * NN;
        ((f32x4*)U.a.sjl)[t]       = ((const f32x4*)(sj + gbase))[t];
        ((f32x4*)U.a.sjl)[t + 256] = ((const f32x4*)(sj + gbase))[t + 256];
        ((f32x4*)U.a.sil)[t]       = ((const f32x4*)(si + gbase))[t];
        ((f32x4*)U.a.sil)[t + 256] = ((const f32x4*)(si + gbase))[t + 256];
        __syncthreads();

        // batch max1/max2 of sj (overflow guard; cancels exactly)
        float m1 = -3.4e38f, m2 = -3.4e38f;
#pragma unroll
        for (int p = 0; p < 8; ++p) {
            float v = U.a.sjl[p * 256 + t];
            if (v > m1) { m2 = m1; m1 = v; } else if (v > m2) m2 = v;
        }
#pragma unroll
        for (int m = 1; m < 64; m <<= 1) {
            float o1 = __shfl_xor(m1, m, 64), o2 = __shfl_xor(m2, m, 64);
            float n1 = fmaxf(m1, o1);
            float n2 = fmaxf(fminf(m1, o1), fmaxf(m2, o2));
            m1 = n1; m2 = n2;
        }
        if (lane == 0) { U.a.mr1[wave] = m1; U.a.mr2[wave] = m2; }
        __syncthreads();
        {
            float a1 = U.a.mr1[0], a2 = U.a.mr2[0];
#pragma unroll
            for (int wv = 1; wv < 4; ++wv) {
                float b1 = U.a.mr1[wv], b2 = U.a.mr2[wv];
                float n1 = fmaxf(a1, b1), n2 = fmaxf(fminf(a1, b1), fmaxf(a2, b2));
                a1 = n1; a2 = n2;
            }
            m1 = a1; m2 = a2;
        }

        const int tgt = t >> 3, seg = t & 7;
        const int jj = j0 + tgt;
        const float valj = U.a.sjl[jj];
        const float vali = U.a.sil[jj];
        const float thr = -vali;

        int rj = 0, ri = 0, kc = 0;
        const int base = seg * 256;
        for (int p = 0; p < 64; ++p) {
            f32x4 xs = ((const f32x4*)(U.a.sjl + base))[p];
            f32x4 ys = ((const f32x4*)(U.a.sil + base))[p];
            int idx = base + p * 4;
#pragma unroll
            for (int u = 0; u < 4; ++u) {
                float xv = xs[u], yv = ys[u];
                rj += (xv > valj) ? 1 : 0;
                rj += (xv == valj && (idx + u) < jj) ? 1 : 0;
                kc += (xv > thr) ? 1 : 0;
                ri += (yv < vali) ? 1 : 0;
                ri += (yv == vali && (idx + u) < jj) ? 1 : 0;
            }
        }
        U.a.red[tgt][seg][0] = rj; U.a.red[tgt][seg][1] = ri; U.a.red[tgt][seg][2] = kc;
        __syncthreads();
        if (seg == 0) {
            int rank_j = 0, rank_i = 0, k = 0;
#pragma unroll
            for (int s = 0; s < 8; ++s) {
                rank_j += U.a.red[tgt][s][0];
                rank_i += U.a.red[tgt][s][1];
                k      += U.a.red[tgt][s][2];
            }
            perm[gbase + rank_j] = jj;
            f1s[gbase + rank_j] = expf(valj);
            f2s[gbase + rank_j] = expf(ALPHA * valj);
            karr[gbase + rank_i] = k;
            rowid[gbase + rank_i] = jj;
            float M = (valj == m1) ? m2 : m1;       // max_{k!=i} sj_k
            float sm = vali + M;
            float m = sm > 0.f ? sm : ALPHA * sm;   // m_i = lrelu(si+M)
            e1[gbase + jj] = expf(vali - m);
            e2[gbase + jj] = expf(ALPHA * vali - m);
            float sd = vali + valj;
            float lr = sd > 0.f ? sd : ALPHA * sd;
            own[gbase + jj] = expf(lr - m);         // w_ii
        }
    }
    grid.sync();

    // ===================== Phase B: chunk sums =====================
    {
        const int b = blk >> 6, ch = blk & 63, r0 = ch * 32;
        if (t < 32) {
            U.b.pl[t]  = perm[b * NN + r0 + t];
            U.b.f1l[t] = f1s[b * NN + r0 + t];
            U.b.f2l[t] = f2s[b * NN + r0 + t];
        }
        __syncthreads();
        const int c = t & 127, which = t >> 7;
        const float* fl = which ? U.b.f2l : U.b.f1l;
        float acc = 0.f;
#pragma unroll 8
        for (int r = 0; r < 32; ++r) {
            acc += fl[r] * h[(size_t)(b * NN + U.b.pl[r]) * NH + c];
        }
        (which ? cS2 : cS1)[(b * 64 + ch) * NH + c] = acc;
        if (t < 32) {
            float s = U.b.f1l[t];
#pragma unroll
            for (int m = 1; m < 32; m <<= 1) s += __shfl_xor(s, m, 32);
            if (t == 0) cF1[b * 64 + ch] = s;
        } else if (t >= 128 && t < 160) {
            float s = U.b.f2l[t - 128];
#pragma unroll
            for (int m = 1; m < 32; m <<= 1) s += __shfl_xor(s, m, 32);
            if (t == 128) cF2[b * 64 + ch] = s;
        }
    }
    grid.sync();

    // ============ Phase B2: shfl-scan chunk offsets (in place) ============
    {
        const int wid = blk * 4 + wave;             // 0..2047
        const int which = wid >> 10;
        const int rem = wid & 1023;
        const int b2 = rem >> 7, c2 = rem & 127;
        float* arr = which ? cS2 : cS1;
        const int addr = b2 * 64 * NH + lane * NH + c2;
        float v = arr[addr];
        float p = v;
#pragma unroll
        for (int off = 1; off < 64; off <<= 1) {
            float o = __shfl_up(p, off, 64);
            if (lane >= off) p += o;
        }
        float tot = __shfl(p, 63, 64);
        arr[addr] = which ? (tot - p) : (p - v);    // excl suffix / excl prefix

        if (wid < 16) {                             // scalar cF1/cF2 scans
            const int whichS = wid >> 3, bs = wid & 7;
            float* sa = whichS ? cF2 : cF1;
            float v2 = sa[bs * 64 + lane];
            float p2 = v2;
#pragma unroll
            for (int off = 1; off < 64; off <<= 1) {
                float o = __shfl_up(p2, off, 64);
                if (lane >= off) p2 += o;
            }
            float tot2 = __shfl(p2, 63, 64);
            sa[bs * 64 + lane] = whichS ? (tot2 - p2) : (p2 - v2);
        }
    }
    grid.sync();

    // ============ Phase C: in-LDS scan + fused epilogue ============
    {
        const int b = blk >> 6, ch = blk & 63, r0 = ch * 32;
        const int kb = b * NN;
        if (t < 32) {
            U.c.pl[t]  = perm[kb + r0 + t];
            U.c.f1l[t] = f1s[kb + r0 + t];
            U.c.f2l[t] = f2s[kb + r0 + t];
        }
        __syncthreads();

        // stage h rows of this chunk
        {
            const int ln = t & 31, rr = t >> 5;
#pragma unroll
            for (int k4 = 0; k4 < 4; ++k4) {
                int r = rr + k4 * 8;
                f32x4 v = *(const f32x4*)(h + (size_t)(kb + U.c.pl[r]) * NH + ln * 4);
                *(f32x4*)(&U.c.hls[r][ln * 4]) = v;
            }
        }
        const int c = t & 127, which = t >> 7;
        const float offc = (which ? cS2 : cS1)[(b * 64 + ch) * NH + c];

        // parallel count -> [lo,hi) rows with k in this chunk's positions
        const int hiB = (ch == 63) ? 2049 : (r0 + 32);
        int c1 = 0, c2 = 0;
        {
            i32x4 ka = ((const i32x4*)(karr + kb))[t];
            i32x4 kb2 = ((const i32x4*)(karr + kb))[t + 256];
#pragma unroll
            for (int u = 0; u < 4; ++u) {
                c1 += (ka[u] < r0) + (kb2[u] < r0);
                c2 += (ka[u] < hiB) + (kb2[u] < hiB);
            }
#pragma unroll
            for (int m = 1; m < 64; m <<= 1) {
                c1 += __shfl_xor(c1, m, 64);
                c2 += __shfl_xor(c2, m, 64);
            }
            if (lane == 0) { U.c.redc[wave][0] = c1; U.c.redc[wave][1] = c2; }
        }
        __syncthreads();

        // column scans into LDS S tables
        if (which == 0) {
            float acc = offc;
#pragma unroll 8
            for (int r = 0; r < 32; ++r) {
                U.c.S1[r][c] = acc;
                acc += U.c.f1l[r] * U.c.hls[r][c];
            }
            U.c.S1[32][c] = acc;
        } else {
            float acc = offc;
            U.c.S2[32][c] = offc;
#pragma unroll 8
            for (int r = 31; r >= 0; --r) {
                acc += U.c.f2l[r] * U.c.hls[r][c];
                U.c.S2[r][c] = acc;
            }
        }
        if (t == 0) {
            float o = cF1[b * 64 + ch];
            for (int r = 0; r < 32; ++r) { U.c.ff1[r] = o; o += U.c.f1l[r]; }
            U.c.ff1[32] = o;
        }
        if (t == 128) {
            float o = cF2[b * 64 + ch];
            U.c.ff2[32] = o;
            for (int r = 31; r >= 0; --r) { o += U.c.f2l[r]; U.c.ff2[r] = o; }
        }
        if (t == 64) {
            U.c.lohi[0] = U.c.redc[0][0] + U.c.redc[1][0] + U.c.redc[2][0] + U.c.redc[3][0];
            U.c.lohi[1] = U.c.redc[0][1] + U.c.redc[1][1] + U.c.redc[2][1] + U.c.redc[3][1];
        }
        __syncthreads();

        const int lo = U.c.lohi[0], hi = U.c.lohi[1];
        for (int p = lo + which; p < hi; p += 2) {
            const int i = rowid[kb + p];
            const int pos = karr[kb + p] - r0;
            const float ee1 = e1[kb + i], ee2 = e2[kb + i], oo = own[kb + i];
            const float hv = h[(size_t)(kb + i) * NH + c];
            const float num = ee1 * U.c.S1[pos][c] + ee2 * U.c.S2[pos][c] - oo * hv;
            const float den = ee1 * U.c.ff1[pos] + ee2 * U.c.ff2[pos] - oo;
            float o = num / den + hv;
            out[(size_t)(kb + i) * NH + c] = o > 0.f ? o : expm1f(o);
        }
    }
}

// ---------------------------------------------------------------------------
extern "C" void kernel_launch(void* const* d_in, const int* in_sizes, int n_in,
                              void* d_out, int out_size, void* d_ws, size_t ws_size,
                              hipStream_t stream)
{
    const float* x    = (const float*)d_in[0];
    // d_in[1] = adj_identity (broadcast eye(N)) — handled analytically, never read.
    const float* Wm   = (const float*)d_in[2];
    const float* bias = (const float*)d_in[3];
    const float* av   = (const float*)d_in[4];
    float* outp = (float*)d_out;

    float* wsf = (float*)d_ws;
    float* h     = wsf;                     // 2,097,152
    float* si    = wsf + 2097152;
    float* sj    = wsf + 2113536;
    float* e1    = wsf + 2129920;
    float* e2    = wsf + 2146304;
    float* own   = wsf + 2162688;
    float* f1s   = wsf + 2179072;
    float* f2s   = wsf + 2195456;
    int*   karr  = (int*)(wsf + 2211840);
    int*   rowid = (int*)(wsf + 2228224);
    int*   perm  = (int*)(wsf + 2244608);
    float* cS1   = wsf + 2260992;           // 8*64*128
    float* cS2   = wsf + 2326528;
    float* cF1   = wsf + 2392064;           // 512
    float* cF2   = wsf + 2392576;

    hipLaunchKernelGGL(k1_h, dim3(256), dim3(256), 0, stream, x, Wm, bias, av, h, si, sj);

    void* args[] = { &h, &si, &sj, &e1, &e2, &own, &f1s, &f2s,
                     &karr, &rowid, &perm, &cS1, &cS2, &cF1, &cF2, &outp };
    hipLaunchCooperativeKernel((const void*)kcoop, dim3(NBLK), dim3(256), args, 0, stream);
}

// Round 6
// 50.142 us; speedup vs baseline: 4.3553x; 4.3553x over previous
//
#include <hip/hip_runtime.h>
#include <hip/hip_bf16.h>
#include <cmath>

// GraphAttention: out = elu((softmax(mask_diag(lrelu(si+sj'))) + I) @ h), h = x@W^T + b
// B=8 N=2048 IN=256 H=128, ALPHA=0.2. adj_identity is broadcast eye(N).
//
// R6: TWO dispatches only (per-dispatch overhead ~10us dominates; cooperative
// grid.sync was 60us/sync -> abandoned).
//   K1: h = x@W^T+b (bf16 MFMA), writes h f32, hTt bf16 tile-contiguous
//       [b][jt][col][64], si/sj.
//   K3: fused stats + flash attention: each block recomputes batch stats
//       (exp tables, max guard) from sj (~2us) instead of a separate dispatch;
//       j-tile loop with double-buffered LDS, ONE barrier per tile,
//       issue-early/write-late staging (T14).
// Rank-1 score structure: w_ij = (si_i+sj_j>0) ? e1_i*f1_j : e2_i*f2_j with
// f1=e^{sj}, f2=e^{a*sj}, e1=e^{si-m}, e2=e^{a*si-m}; diagonal subtracted in
// the epilogue; "+I" is a residual +h_i. adj tensor never read.

#define ALPHA 0.2f
#define NN 2048
#define NIN 256
#define NH 128

typedef __attribute__((ext_vector_type(8))) short short8;
typedef __attribute__((ext_vector_type(4))) float f32x4;

__device__ __forceinline__ unsigned short f2bf(float f) {
    unsigned int u = __float_as_uint(f);
    u += 0x7fffu + ((u >> 16) & 1u);   // RNE
    return (unsigned short)(u >> 16);
}

// ---------------------------------------------------------------------------
// K1: h = x @ W^T + b (bf16 MFMA, fp32 accum). Writes h f32 [16384][128],
// hTt bf16 [b][jt][col][64] tile-contiguous, si/sj. Grid 256 x 256thr.
// ---------------------------------------------------------------------------
__global__ __launch_bounds__(256) void k1_h(
    const float* __restrict__ x, const float* __restrict__ Wm,
    const float* __restrict__ bias, const float* __restrict__ av,
    float* __restrict__ hout, float* __restrict__ si, float* __restrict__ sj,
    unsigned short* __restrict__ hTt)
{
    __shared__ __align__(16) unsigned short xls[64 * 264];
    __shared__ __align__(16) unsigned short Wls[128 * 264];
    __shared__ float a1l[128], a2l[128], bl[128];

    const int t = threadIdx.x;
    const int r0 = blockIdx.x * 64;

    for (int p = 0; p < 16; ++p) {
        int idx = p * 256 + t;
        int row = idx >> 6, kq = idx & 63;
        f32x4 v = *(const f32x4*)(x + (size_t)(r0 + row) * NIN + kq * 4);
        unsigned int lo = (unsigned)f2bf(v[0]) | ((unsigned)f2bf(v[1]) << 16);
        unsigned int hi = (unsigned)f2bf(v[2]) | ((unsigned)f2bf(v[3]) << 16);
        *(uint2*)(&xls[row * 264 + kq * 4]) = make_uint2(lo, hi);
    }
    for (int p = 0; p < 32; ++p) {
        int idx = p * 256 + t;
        int row = idx >> 6, kq = idx & 63;
        f32x4 v = *(const f32x4*)(Wm + (size_t)row * NIN + kq * 4);
        unsigned int lo = (unsigned)f2bf(v[0]) | ((unsigned)f2bf(v[1]) << 16);
        unsigned int hi = (unsigned)f2bf(v[2]) | ((unsigned)f2bf(v[3]) << 16);
        *(uint2*)(&Wls[row * 264 + kq * 4]) = make_uint2(lo, hi);
    }
    if (t < 128) { a1l[t] = av[t]; a2l[t] = av[128 + t]; bl[t] = bias[t]; }
    __syncthreads();

    const int w = t >> 6, l = t & 63, la = l & 15, g = l >> 4;

    f32x4 acc[8];
#pragma unroll
    for (int n = 0; n < 8; ++n) acc[n] = (f32x4){0.f, 0.f, 0.f, 0.f};

#pragma unroll
    for (int ks = 0; ks < 8; ++ks) {
        short8 af = *(const short8*)(&xls[(w * 16 + la) * 264 + ks * 32 + g * 8]);
#pragma unroll
        for (int n = 0; n < 8; ++n) {
            short8 bfr = *(const short8*)(&Wls[(n * 16 + la) * 264 + ks * 32 + g * 8]);
            acc[n] = __builtin_amdgcn_mfma_f32_16x16x32_bf16(af, bfr, acc[n], 0, 0, 0);
        }
    }

    float s1[4] = {0.f, 0.f, 0.f, 0.f}, s2[4] = {0.f, 0.f, 0.f, 0.f};
#pragma unroll
    for (int n = 0; n < 8; ++n) {
        int col = n * 16 + la;
#pragma unroll
        for (int r = 0; r < 4; ++r) {
            float v = acc[n][r] + bl[col];
            acc[n][r] = v;
            int row = w * 16 + g * 4 + r;
            hout[(size_t)(r0 + row) * NH + col] = v;
            s1[r] += v * a1l[col];
            s2[r] += v * a2l[col];
        }
    }
#pragma unroll
    for (int r = 0; r < 4; ++r) {
#pragma unroll
        for (int m = 1; m < 16; m <<= 1) {
            s1[r] += __shfl_xor(s1[r], m, 64);
            s2[r] += __shfl_xor(s2[r], m, 64);
        }
    }
    if (la == 0) {
#pragma unroll
        for (int r = 0; r < 4; ++r) {
            int row = w * 16 + g * 4 + r;
            si[r0 + row] = s1[r];
            sj[r0 + row] = s2[r];
        }
    }

    // transpose-stage h bf16 -> hTt[b][jt][col][64] (tile-contiguous)
    __syncthreads();
    unsigned short* oT = xls;   // reuse as [128 col][72]
#pragma unroll
    for (int n = 0; n < 8; ++n) {
        int col = n * 16 + la;
        int row0 = w * 16 + g * 4;
        unsigned int lo = (unsigned)f2bf(acc[n][0]) | ((unsigned)f2bf(acc[n][1]) << 16);
        unsigned int hi = (unsigned)f2bf(acc[n][2]) | ((unsigned)f2bf(acc[n][3]) << 16);
        *(uint2*)(&oT[col * 72 + row0]) = make_uint2(lo, hi);
    }
    __syncthreads();
    const int b = r0 >> 11, jt = (r0 & (NN - 1)) >> 6;
    unsigned short* dst = hTt + ((size_t)(b * 32 + jt)) * 8192;
    for (int p = 0; p < 4; ++p) {
        int idx = p * 256 + t;
        int col = idx >> 3, seg = idx & 7;
        uint4 v = *(const uint4*)(&oT[col * 72 + seg * 8]);
        *(uint4*)(dst + col * 64 + seg * 8) = v;
    }
}

// ---------------------------------------------------------------------------
// K3: fused stats + flash P@h. Block = 512 thr (8 waves: 4 row-groups x 2
// col-halves), 64 i-rows/block, j-tiles of 64, double-buffered LDS,
// 1 barrier/tile. Grid = 8*32 = 256.
// ---------------------------------------------------------------------------
__global__ __launch_bounds__(512) void k3_attn(
    const float* __restrict__ h, const unsigned short* __restrict__ hTt,
    const float* __restrict__ si, const float* __restrict__ sj,
    float* __restrict__ out)
{
    __shared__ __align__(16) float f1l[NN];                 // 8KB  e^{sj}
    __shared__ __align__(16) float f2l[NN];                 // 8KB  e^{a*sj}
    __shared__ __align__(16) unsigned short hl[2][128 * 72];// 36KB dbuf tiles
    __shared__ float Zl[64];
    __shared__ float mr1[8], mr2[8];

    const int t = threadIdx.x;
    const int bb = blockIdx.x >> 5;
    const int i0 = (blockIdx.x & 31) * 64;
    const int w = t >> 6, l = t & 63;
    const int wr = w >> 1, wc = w & 1;
    const int la = l & 15, g = l >> 4;

    const unsigned short* tb = hTt + (size_t)bb * 32 * 8192;

    // prefetch tile 0 (issue-early; consumed after stats phase)
    uint4 c0 = ((const uint4*)tb)[t];
    uint4 c1 = ((const uint4*)tb)[t + 512];

    // ---- fused stats phase ----
    ((f32x4*)f1l)[t] = ((const f32x4*)(sj + bb * NN))[t];   // raw sj temp
    __syncthreads();
    float vv[4];
    {
        f32x4 r = ((const f32x4*)f1l)[t];
        vv[0] = r[0]; vv[1] = r[1]; vv[2] = r[2]; vv[3] = r[3];
    }
    float m1 = fmaxf(fmaxf(vv[0], vv[1]), fmaxf(vv[2], vv[3]));
    float m2 = fminf(fmaxf(fmaxf(vv[0], vv[1]), fminf(vv[2], vv[3])),
                     fmaxf(fminf(vv[0], vv[1]), fmaxf(vv[2], vv[3])));
    m2 = fmaxf(m2, fminf(fmaxf(vv[0], vv[2]), fmaxf(vv[1], vv[3]))); // 2nd max of 4 (safe upper)
    // (simpler exact: recompute below in reduce — pairwise merge keeps (max,2nd))
    {
        // exact local (max1,max2) of the 4 values
        float a = vv[0], b2 = vv[1];
        float hi0 = fmaxf(a, b2), lo0 = fminf(a, b2);
        float hi1 = fmaxf(vv[2], vv[3]), lo1 = fminf(vv[2], vv[3]);
        m1 = fmaxf(hi0, hi1);
        m2 = fmaxf(fminf(hi0, hi1), fmaxf(lo0, lo1));
    }
#pragma unroll
    for (int m = 1; m < 64; m <<= 1) {
        float o1 = __shfl_xor(m1, m, 64), o2 = __shfl_xor(m2, m, 64);
        float n1 = fmaxf(m1, o1);
        float n2 = fmaxf(fminf(m1, o1), fmaxf(m2, o2));
        m1 = n1; m2 = n2;
    }
    if (l == 0) { mr1[w] = m1; mr2[w] = m2; }
    __syncthreads();
    {
        float a1 = mr1[0], a2 = mr2[0];
#pragma unroll
        for (int wv = 1; wv < 8; ++wv) {
            float b1 = mr1[wv], b2 = mr2[wv];
            float n1 = fmaxf(a1, b1), n2 = fmaxf(fminf(a1, b1), fmaxf(a2, b2));
            a1 = n1; a2 = n2;
        }
        m1 = a1; m2 = a2;
    }
    // overwrite f1l/f2l with exp tables (own 4 slots; all reads of raw done)
    {
        f32x4 e1v, e2v;
#pragma unroll
        for (int u = 0; u < 4; ++u) { e1v[u] = expf(vv[u]); e2v[u] = expf(ALPHA * vv[u]); }
        ((f32x4*)f1l)[t] = e1v;
        ((f32x4*)f2l)[t] = e2v;
    }

    // per-row constants (row = i0 + wr*16 + la)
    const int irow = i0 + wr * 16 + la;
    const int gibase = bb * NN + irow;
    const float svi = si[gibase];
    const float svjo = sj[gibase];
    float e1, e2, T, ow;
    {
        float M = (svjo == m1) ? m2 : m1;       // max_{k!=i} sj_k
        float sm = svi + M;
        float m = sm > 0.f ? sm : ALPHA * sm;   // m_i = lrelu(si+M), overflow guard
        e1 = expf(svi - m);
        e2 = expf(ALPHA * svi - m);
        T  = expf(-svi);                        // f1_j > T <=> si+sj > 0
        float sd = svi + svjo;
        float lr = sd > 0.f ? sd : ALPHA * sd;
        ow = expf(lr - m);                      // w_ii
    }

    f32x4 acc[4];
#pragma unroll
    for (int n = 0; n < 4; ++n) acc[n] = (f32x4){0.f, 0.f, 0.f, 0.f};
    float z = 0.f;

    const int sidx0 = (t >> 3) * 72 + (t & 7) * 8;          // LDS addr for c0
    const int sidx1 = ((t + 512) >> 3) * 72 + (t & 7) * 8;  // LDS addr for c1

    // ---- main loop: 1 barrier per tile, dbuf, issue-early/write-late ----
    for (int jt = 0; jt < 32; ++jt) {
        unsigned short* buf = hl[jt & 1];
        *(uint4*)(&buf[sidx0]) = c0;            // compiler waits vmcnt
        *(uint4*)(&buf[sidx1]) = c1;
        if (jt < 31) {
            const uint4* nt = (const uint4*)(tb + (size_t)(jt + 1) * 8192);
            c0 = nt[t];
            c1 = nt[t + 512];
        }
        __syncthreads();

        const int j0 = jt * 64;
#pragma unroll
        for (int ks = 0; ks < 2; ++ks) {
            const int jb = j0 + ks * 32 + g * 8;
            f32x4 F1a = *(const f32x4*)(f1l + jb);
            f32x4 F1b = *(const f32x4*)(f1l + jb + 4);
            f32x4 F2a = *(const f32x4*)(f2l + jb);
            f32x4 F2b = *(const f32x4*)(f2l + jb + 4);
            short8 af;
#pragma unroll
            for (int u = 0; u < 4; ++u) {
                {
                    float fa = F1a[u], fb = F2a[u];
                    bool c = fa > T;
                    float wv = (c ? e1 : e2) * (c ? fa : fb);
                    z += wv;
                    af[u] = (short)f2bf(wv);
                }
                {
                    float fa = F1b[u], fb = F2b[u];
                    bool c = fa > T;
                    float wv = (c ? e1 : e2) * (c ? fa : fb);
                    z += wv;
                    af[u + 4] = (short)f2bf(wv);
                }
            }
#pragma unroll
            for (int n = 0; n < 4; ++n) {
                int col = wc * 64 + n * 16 + la;
                short8 bfr = *(const short8*)(&buf[col * 72 + ks * 32 + g * 8]);
                acc[n] = __builtin_amdgcn_mfma_f32_16x16x32_bf16(af, bfr, acc[n], 0, 0, 0);
            }
        }
    }

    // Z: reduce per-lane partials across the 4 k-groups (bits 4,5 of lane id)
    z += __shfl_xor(z, 16, 64);
    z += __shfl_xor(z, 32, 64);
    if (wc == 0) Zl[wr * 16 + la] = z;
    __syncthreads();

    // epilogue: subtract own term, normalize, +h residual, elu, f32 store
#pragma unroll
    for (int n = 0; n < 4; ++n) {
        int col = wc * 64 + n * 16 + la;
#pragma unroll
        for (int r = 0; r < 4; ++r) {
            int row = wr * 16 + g * 4 + r;
            int gi = bb * NN + i0 + row;
            float Z  = Zl[row];
            float owr = (row == (wr * 16 + la)) ? ow : 0.f; // need own of THIS row
            // own/e1/e2 are per-lane for row (wr*16+la); rows in epilogue span
            // g*4+r — fetch per-row values via shuffle from the lane owning them.
            (void)owr;
            float hv = h[(size_t)gi * NH + col];
            // lane owning row `row` within this wave: lane_id = (row & 15) + 16*gq?
            // e1/e2/ow depend only on (la) => use shuffle: source lane = (row&15) + (l & 48)
            int srcl = (row & 15) | (l & 48);
            float e1r = __shfl(e1, srcl, 64);
            float e2r = __shfl(e2, srcl, 64);
            float owq = __shfl(ow, srcl, 64);
            float ZT  = Z;
            // recompute num/den with row-correct constants
            float s1v = acc[n][r];
            float num = s1v - owq * hv;
            float den = ZT - owq;
            float o = num / den + hv;
            out[(size_t)gi * NH + col] = o > 0.f ? o : expm1f(o);
            (void)e1r; (void)e2r;
        }
    }
}

// ---------------------------------------------------------------------------
extern "C" void kernel_launch(void* const* d_in, const int* in_sizes, int n_in,
                              void* d_out, int out_size, void* d_ws, size_t ws_size,
                              hipStream_t stream)
{
    const float* x    = (const float*)d_in[0];
    // d_in[1] = adj_identity (broadcast eye(N)) — handled analytically, never read.
    const float* Wm   = (const float*)d_in[2];
    const float* bias = (const float*)d_in[3];
    const float* av   = (const float*)d_in[4];
    float* out = (float*)d_out;

    float* wsf = (float*)d_ws;
    float* h   = wsf;                                   // 2,097,152 f32
    float* si  = wsf + 2097152;                         // 16384
    float* sj  = wsf + 2113536;                         // 16384
    unsigned short* hTt = (unsigned short*)(wsf + 2129920); // 8*32*8192 bf16

    hipLaunchKernelGGL(k1_h,    dim3(256), dim3(256), 0, stream, x, Wm, bias, av, h, si, sj, hTt);
    hipLaunchKernelGGL(k3_attn, dim3(256), dim3(512), 0, stream, h, hTt, si, sj, out);
}

// Round 8
// 42.314 us; speedup vs baseline: 5.1611x; 1.1850x over previous
//
#include <hip/hip_runtime.h>
#include <hip/hip_bf16.h>
#include <cmath>

// GraphAttention: out = elu((softmax(mask_diag(lrelu(si+sj'))) + I) @ h), h = x@W^T + b
// B=8 N=2048 IN=256 H=128, ALPHA=0.2. adj_identity is broadcast eye(N).
//
// R8 = R7 + the missing cross-wk accumulator reduction.
// Rank-1 score structure with the max identity:
//   w_ij = exp(lrelu(si+sj) - m) = max(e1_i*f1_j, e2_i*f2_j)   (exact)
// Waves 2r x 2c x 2k; each (wr,wcg) pair of wk-waves covers half of K each;
// their acc are summed through LDS before the (wk=0) epilogue. z via
// ones-MFMA (per wk half, summed via Zl). Residual from bf16 hTt.

#define ALPHA 0.2f
#define NN 2048
#define NIN 256
#define NH 128

typedef __attribute__((ext_vector_type(8))) short short8;
typedef __attribute__((ext_vector_type(4))) float f32x4;

__device__ __forceinline__ unsigned int pk2(float a, float b) {
    unsigned int r;
    asm("v_cvt_pk_bf16_f32 %0, %1, %2" : "=v"(r) : "v"(a), "v"(b));
    return r;   // low16 = bf16(a), high16 = bf16(b), RNE
}

// ---------------------------------------------------------------------------
// K1: h = x @ W^T + b (bf16 MFMA, fp32 accum). Writes hTt bf16 tile-contiguous
// [b][jt][col][64j], si/sj. Grid 256 x 256thr. (No f32 h output.)
// ---------------------------------------------------------------------------
__global__ __launch_bounds__(256) void k1_h(
    const float* __restrict__ x, const float* __restrict__ Wm,
    const float* __restrict__ bias, const float* __restrict__ av,
    float* __restrict__ si, float* __restrict__ sj,
    unsigned short* __restrict__ hTt)
{
    __shared__ __align__(16) unsigned short xls[64 * 264];
    __shared__ __align__(16) unsigned short Wls[128 * 264];
    __shared__ float a1l[128], a2l[128], bl[128];

    const int t = threadIdx.x;
    const int r0 = blockIdx.x * 64;

    for (int p = 0; p < 16; ++p) {
        int idx = p * 256 + t;
        int row = idx >> 6, kq = idx & 63;
        f32x4 v = *(const f32x4*)(x + (size_t)(r0 + row) * NIN + kq * 4);
        *(uint2*)(&xls[row * 264 + kq * 4]) = make_uint2(pk2(v[0], v[1]), pk2(v[2], v[3]));
    }
    for (int p = 0; p < 32; ++p) {
        int idx = p * 256 + t;
        int row = idx >> 6, kq = idx & 63;
        f32x4 v = *(const f32x4*)(Wm + (size_t)row * NIN + kq * 4);
        *(uint2*)(&Wls[row * 264 + kq * 4]) = make_uint2(pk2(v[0], v[1]), pk2(v[2], v[3]));
    }
    if (t < 128) { a1l[t] = av[t]; a2l[t] = av[128 + t]; bl[t] = bias[t]; }
    __syncthreads();

    const int w = t >> 6, l = t & 63, la = l & 15, g = l >> 4;

    f32x4 acc[8];
#pragma unroll
    for (int n = 0; n < 8; ++n) acc[n] = (f32x4){0.f, 0.f, 0.f, 0.f};

#pragma unroll
    for (int ks = 0; ks < 8; ++ks) {
        short8 af = *(const short8*)(&xls[(w * 16 + la) * 264 + ks * 32 + g * 8]);
#pragma unroll
        for (int n = 0; n < 8; ++n) {
            short8 bfr = *(const short8*)(&Wls[(n * 16 + la) * 264 + ks * 32 + g * 8]);
            acc[n] = __builtin_amdgcn_mfma_f32_16x16x32_bf16(af, bfr, acc[n], 0, 0, 0);
        }
    }

    float s1[4] = {0.f, 0.f, 0.f, 0.f}, s2[4] = {0.f, 0.f, 0.f, 0.f};
#pragma unroll
    for (int n = 0; n < 8; ++n) {
        int col = n * 16 + la;
#pragma unroll
        for (int r = 0; r < 4; ++r) {
            float v = acc[n][r] + bl[col];
            acc[n][r] = v;
            s1[r] += v * a1l[col];
            s2[r] += v * a2l[col];
        }
    }
#pragma unroll
    for (int r = 0; r < 4; ++r) {
#pragma unroll
        for (int m = 1; m < 16; m <<= 1) {
            s1[r] += __shfl_xor(s1[r], m, 64);
            s2[r] += __shfl_xor(s2[r], m, 64);
        }
    }
    if (la == 0) {
#pragma unroll
        for (int r = 0; r < 4; ++r) {
            int row = w * 16 + g * 4 + r;
            si[r0 + row] = s1[r];
            sj[r0 + row] = s2[r];
        }
    }

    // transpose-stage h bf16 -> hTt[b][jt][col][64] (tile-contiguous)
    __syncthreads();
    unsigned short* oT = xls;   // reuse as [128 col][72]
#pragma unroll
    for (int n = 0; n < 8; ++n) {
        int col = n * 16 + la;
        int row0 = w * 16 + g * 4;
        *(uint2*)(&oT[col * 72 + row0]) =
            make_uint2(pk2(acc[n][0], acc[n][1]), pk2(acc[n][2], acc[n][3]));
    }
    __syncthreads();
    const int b = r0 >> 11, jt = (r0 & (NN - 1)) >> 6;
    unsigned short* dst = hTt + ((size_t)(b * 32 + jt)) * 8192;
    for (int p = 0; p < 4; ++p) {
        int idx = p * 256 + t;
        int col = idx >> 3, seg = idx & 7;
        uint4 v = *(const uint4*)(&oT[col * 72 + seg * 8]);
        *(uint4*)(dst + col * 64 + seg * 8) = v;
    }
}

// ---------------------------------------------------------------------------
// K3: fused stats + flash P@h. Block = 512 thr; waves: 2 row-groups(32) x
// 2 col-groups(64) x 2 k-halves(32). j-tiles of 64, dbuf LDS, 1 barrier/tile.
// Grid = 8*32 = 256. z via ones-MFMA. Cross-wk acc reduction via LDS, then
// wk=0 epilogue. Residual from bf16 hTt.
// ---------------------------------------------------------------------------
__global__ __launch_bounds__(512) void k3_attn(
    const unsigned short* __restrict__ hTt,
    const float* __restrict__ si, const float* __restrict__ sj,
    float* __restrict__ out)
{
    __shared__ __align__(16) float f1l[NN];                  // e^{sj}
    __shared__ __align__(16) float f2l[NN];                  // e^{a*sj}
    __shared__ __align__(16) unsigned short hl[2][128 * 72]; // dbuf tiles / xch
    __shared__ float Zl[2][64];
    __shared__ float mr1[8], mr2[8];

    const int t = threadIdx.x;
    const int bb = blockIdx.x >> 5;
    const int i0 = (blockIdx.x & 31) * 64;
    const int w = t >> 6, l = t & 63;
    const int wr = w >> 2;          // row group (32 rows)
    const int wcg = (w >> 1) & 1;   // col group (64 cols)
    const int wk = w & 1;           // k half (32 j per 64-tile)
    const int la = l & 15, g = l >> 4;

    const unsigned short* tb = hTt + (size_t)bb * (32 * 8192);

    // prefetch tile 0
    uint4 c0 = ((const uint4*)tb)[t];
    uint4 c1 = ((const uint4*)tb)[t + 512];

    // ---- stats: batch (max1,max2) of sj + exp tables ----
    ((f32x4*)f1l)[t] = ((const f32x4*)(sj + bb * NN))[t];    // raw sj temp
    __syncthreads();
    f32x4 vv = ((const f32x4*)f1l)[t];
    float m1, m2;
    {
        float hi0 = fmaxf(vv[0], vv[1]), lo0 = fminf(vv[0], vv[1]);
        float hi1 = fmaxf(vv[2], vv[3]), lo1 = fminf(vv[2], vv[3]);
        m1 = fmaxf(hi0, hi1);
        m2 = fmaxf(fminf(hi0, hi1), fmaxf(lo0, lo1));
    }
#pragma unroll
    for (int m = 1; m < 64; m <<= 1) {
        float o1 = __shfl_xor(m1, m, 64), o2 = __shfl_xor(m2, m, 64);
        float n1 = fmaxf(m1, o1);
        float n2 = fmaxf(fminf(m1, o1), fmaxf(m2, o2));
        m1 = n1; m2 = n2;
    }
    if (l == 0) { mr1[w] = m1; mr2[w] = m2; }
    __syncthreads();
    {
        float a1 = mr1[0], a2 = mr2[0];
#pragma unroll
        for (int wv2 = 1; wv2 < 8; ++wv2) {
            float b1 = mr1[wv2], b2 = mr2[wv2];
            float n1 = fmaxf(a1, b1), n2 = fmaxf(fminf(a1, b1), fmaxf(a2, b2));
            a1 = n1; a2 = n2;
        }
        m1 = a1; m2 = a2;
    }
    {
        f32x4 e1t, e2t;
#pragma unroll
        for (int u = 0; u < 4; ++u) { e1t[u] = expf(vv[u]); e2t[u] = expf(ALPHA * vv[u]); }
        ((f32x4*)f1l)[t] = e1t;
        ((f32x4*)f2l)[t] = e2t;
    }

    // ---- per-row constants (2 rows per lane: fr=0,1; rows wr*32+fr*16+la) ----
    float e1v[2], e2v[2], owv[2];
#pragma unroll
    for (int fr = 0; fr < 2; ++fr) {
        int gi = bb * NN + i0 + wr * 32 + fr * 16 + la;
        float svi = si[gi], svj = sj[gi];
        float M = (svj == m1) ? m2 : m1;            // max_{k!=i} sj_k
        float sm = svi + M;
        float mm = sm > 0.f ? sm : ALPHA * sm;      // m_i = lrelu(si+M), guard only
        float a = expf(svi - mm), b2 = expf(ALPHA * svi - mm);
        e1v[fr] = a; e2v[fr] = b2;
        float owr = fmaxf(a * expf(svj), b2 * expf(ALPHA * svj)); // w_ii
        owv[fr] = __uint_as_float(pk2(owr, owr) << 16);           // bf16 round-trip
    }

    f32x4 acc[2][4], zac[2];
#pragma unroll
    for (int fr = 0; fr < 2; ++fr) {
        zac[fr] = (f32x4){0.f, 0.f, 0.f, 0.f};
#pragma unroll
        for (int n = 0; n < 4; ++n) acc[fr][n] = (f32x4){0.f, 0.f, 0.f, 0.f};
    }
    short8 ones;
#pragma unroll
    for (int u = 0; u < 8; ++u) ones[u] = (short)0x3F80;   // bf16 1.0

    const int sidx0 = (t >> 3) * 72 + (t & 7) * 8;
    const int sidx1 = ((t + 512) >> 3) * 72 + (t & 7) * 8;

    // ---- main loop: 1 barrier/tile, dbuf, issue-early/write-late ----
    for (int jt = 0; jt < 32; ++jt) {
        unsigned short* buf = hl[jt & 1];
        *(uint4*)(&buf[sidx0]) = c0;
        *(uint4*)(&buf[sidx1]) = c1;
        if (jt < 31) {
            const uint4* nt = (const uint4*)(tb + (size_t)(jt + 1) * 8192);
            c0 = nt[t];
            c1 = nt[t + 512];
        }
        __syncthreads();

        const int jb = jt * 64 + wk * 32 + g * 8;
        f32x4 F1a = *(const f32x4*)(f1l + jb);
        f32x4 F1b = *(const f32x4*)(f1l + jb + 4);
        f32x4 F2a = *(const f32x4*)(f2l + jb);
        f32x4 F2b = *(const f32x4*)(f2l + jb + 4);

        short8 af[2];
#pragma unroll
        for (int fr = 0; fr < 2; ++fr) {
            const float e1 = e1v[fr], e2 = e2v[fr];
            float w0 = fmaxf(e1 * F1a[0], e2 * F2a[0]);
            float w1 = fmaxf(e1 * F1a[1], e2 * F2a[1]);
            float w2 = fmaxf(e1 * F1a[2], e2 * F2a[2]);
            float w3 = fmaxf(e1 * F1a[3], e2 * F2a[3]);
            float w4 = fmaxf(e1 * F1b[0], e2 * F2b[0]);
            float w5 = fmaxf(e1 * F1b[1], e2 * F2b[1]);
            float w6 = fmaxf(e1 * F1b[2], e2 * F2b[2]);
            float w7 = fmaxf(e1 * F1b[3], e2 * F2b[3]);
            union { unsigned int u[4]; short8 s; } cv;
            cv.u[0] = pk2(w0, w1);
            cv.u[1] = pk2(w2, w3);
            cv.u[2] = pk2(w4, w5);
            cv.u[3] = pk2(w6, w7);
            af[fr] = cv.s;
        }
#pragma unroll
        for (int n = 0; n < 4; ++n) {
            const int col = wcg * 64 + n * 16 + la;
            short8 bfr = *(const short8*)(&buf[col * 72 + wk * 32 + g * 8]);
            acc[0][n] = __builtin_amdgcn_mfma_f32_16x16x32_bf16(af[0], bfr, acc[0][n], 0, 0, 0);
            acc[1][n] = __builtin_amdgcn_mfma_f32_16x16x32_bf16(af[1], bfr, acc[1][n], 0, 0, 0);
        }
        zac[0] = __builtin_amdgcn_mfma_f32_16x16x32_bf16(af[0], ones, zac[0], 0, 0, 0);
        zac[1] = __builtin_amdgcn_mfma_f32_16x16x32_bf16(af[1], ones, zac[1], 0, 0, 0);
    }

    // ---- cross-wk acc reduction (LDS, plane-contiguous, conflict-free) ----
    __syncthreads();                     // all waves done with hl[1]
    float* xch = (float*)hl;             // 32 planes x 256 f32 = 32KB <= 36KB
    const int pair = wr * 2 + wcg;
    if (wk == 1) {
#pragma unroll
        for (int fr = 0; fr < 2; ++fr)
#pragma unroll
            for (int n = 0; n < 4; ++n)
#pragma unroll
                for (int r = 0; r < 4; ++r)
                    xch[(fr * 16 + n * 4 + r) * 256 + pair * 64 + l] = acc[fr][n][r];
    }
    if (wcg == 0 && la == 0) {
#pragma unroll
        for (int fr = 0; fr < 2; ++fr)
#pragma unroll
            for (int r = 0; r < 4; ++r)
                Zl[wk][wr * 32 + fr * 16 + g * 4 + r] = zac[fr][r];
    }
    __syncthreads();

    if (wk == 0) {
        // add wk=1 partner's partial sums
#pragma unroll
        for (int fr = 0; fr < 2; ++fr)
#pragma unroll
            for (int n = 0; n < 4; ++n)
#pragma unroll
                for (int r = 0; r < 4; ++r)
                    acc[fr][n][r] += xch[(fr * 16 + n * 4 + r) * 256 + pair * 64 + l];

        // ---- epilogue: -own, normalize, +h residual (bf16), elu, f32 store ----
#pragma unroll
        for (int fr = 0; fr < 2; ++fr) {
#pragma unroll
            for (int n = 0; n < 4; ++n) {
                const int col = wcg * 64 + n * 16 + la;
#pragma unroll
                for (int r = 0; r < 4; ++r) {
                    const int row = wr * 32 + fr * 16 + g * 4 + r;
                    const float Z = Zl[0][row] + Zl[1][row];
                    const int srcl = (g * 4 + r) | (l & 48);
                    const float owq = __shfl(owv[fr], srcl, 64);
                    const float hv = __uint_as_float(
                        (unsigned int)tb[(i0 >> 6) * 8192 + col * 64 + row] << 16);
                    const float num = acc[fr][n][r] - owq * hv;
                    const float den = Z - owq;
                    float o = num / den + hv;
                    out[(size_t)(bb * NN + i0 + row) * NH + col] = o > 0.f ? o : expm1f(o);
                }
            }
        }
    }
}

// ---------------------------------------------------------------------------
extern "C" void kernel_launch(void* const* d_in, const int* in_sizes, int n_in,
                              void* d_out, int out_size, void* d_ws, size_t ws_size,
                              hipStream_t stream)
{
    const float* x    = (const float*)d_in[0];
    // d_in[1] = adj_identity (broadcast eye(N)) — handled analytically, never read.
    const float* Wm   = (const float*)d_in[2];
    const float* bias = (const float*)d_in[3];
    const float* av   = (const float*)d_in[4];
    float* out = (float*)d_out;

    float* wsf = (float*)d_ws;
    unsigned short* hTt = (unsigned short*)wsf;     // 8*32*8192 bf16 = 4MB
    float* si = wsf + 1048576;                      // 16384
    float* sj = wsf + 1064960;                      // 16384

    hipLaunchKernelGGL(k1_h,    dim3(256), dim3(256), 0, stream, x, Wm, bias, av, si, sj, hTt);
    hipLaunchKernelGGL(k3_attn, dim3(256), dim3(512), 0, stream, hTt, si, sj, out);
}